// Round 1
// 136.133 us; speedup vs baseline: 1.5752x; 1.5752x over previous
//
#include <hip/hip_runtime.h>

#define GAT_B   8
#define GAT_N   1024
#define GAT_DIN 256
#define GAT_H   8
#define GAT_HD  32

typedef unsigned short gu16;
typedef unsigned int   gu32;
typedef __bf16 bf16x8 __attribute__((ext_vector_type(8)));
typedef __bf16 bf16x4 __attribute__((ext_vector_type(4)));
typedef float  f32x4v __attribute__((ext_vector_type(4)));

__device__ __forceinline__ float gb2f(gu16 u) { return __uint_as_float(((gu32)u) << 16); }

// Per-kernel input-dtype self-detection. bf16 N(0,1): exponent field <= ~131
// in every u16. fp32 viewed as u16 pairs: mantissa halves have near-uniform
// exponent bits, so P(no exponent >= 140 in 128 words) < 1e-14.
__device__ __forceinline__ int gat_is_fp32(const gu16* p) {
    int bad = 0;
    for (int i = 0; i < 128; ++i) {
        int e = (p[i] >> 7) & 0xFF;
        if (e >= 140) bad = 1;
    }
    return bad;
}

// ---------------------------------------------------------------------------
// Kernel 1 (MFMA): Wh = X @ W[h] per head, written as bf16 in B-fragment
// layout WhbF[b][h][jc(32)][kg(4)][col(32)][e(8)], element = Wh[jc*32+kg*8+e][col].
// Also e1 = Wh.a1, e2 = Wh.a2 (fp32).
// Block = 256 thr = 4 waves, all same head h, 4 consecutive 16-row tiles.
// grid = 128 tile-groups x 8 heads = 1024 blocks. LDS: W[h] staged in frag
// layout, 16 KB bf16.
// ---------------------------------------------------------------------------
__global__ __launch_bounds__(256) void CustomGATLayer_90348932038855_kernel(
    const void* __restrict__ Xv, const void* __restrict__ Wv, const void* __restrict__ Av,
    __bf16* __restrict__ whb, float* __restrict__ e1, float* __restrict__ e2)
{
    __shared__ __align__(16) __bf16 WlF[GAT_DIN * GAT_HD];   // 8192 elems = 16 KB
    __shared__ int sflag;

    const int t  = threadIdx.x;
    const int id = blockIdx.x;
    const int h  = id & 7;
    const int mg = id >> 3;                 // 0..127

    if (t == 0) sflag = gat_is_fp32((const gu16*)Xv);
    __syncthreads();
    const int fp32 = sflag;

    // Stage W[h] (256x32) into fragment layout: dst ((kc*4+g)*32 + k)*8 + e,
    // where source row i = kc*32 + g*8 + e, col k.
    if (fp32) {
        const float* ws = (const float*)Wv + (size_t)h * GAT_DIN * GAT_HD;
        #pragma unroll
        for (int q = 0; q < 8; ++q) {
            int idx = q * 1024 + t * 4;
            int i = idx >> 5, k = idx & 31;
            float4 v = *(const float4*)(ws + idx);
            int d = (((i >> 5) * 4 + ((i >> 3) & 3)) * 32 + k) * 8 + (i & 7);
            WlF[d] = (__bf16)v.x; WlF[d + 8]  = (__bf16)v.y;
            WlF[d + 16] = (__bf16)v.z; WlF[d + 24] = (__bf16)v.w;
        }
    } else {
        const gu16* ws = (const gu16*)Wv + (size_t)h * GAT_DIN * GAT_HD;
        gu16* wl = (gu16*)WlF;
        #pragma unroll
        for (int q = 0; q < 8; ++q) {
            int idx = q * 1024 + t * 4;
            int i = idx >> 5, k = idx & 31;
            ushort4 v = *(const ushort4*)(ws + idx);
            int d = (((i >> 5) * 4 + ((i >> 3) & 3)) * 32 + k) * 8 + (i & 7);
            wl[d] = v.x; wl[d + 8] = v.y; wl[d + 16] = v.z; wl[d + 24] = v.w;
        }
    }
    __syncthreads();

    const int wid = t >> 6, l = t & 63, g = l >> 4, c = l & 15;
    const int mt   = mg * 4 + wid;          // 0..511 (16-row tile over B*N)
    const int M0   = mt * 16;
    const int b    = M0 >> 10;
    const int nloc = M0 & 1023;
    const int row  = nloc + c;              // A-fragment row (lane&15)

    f32x4v acc0 = {0.f, 0.f, 0.f, 0.f};
    f32x4v acc1 = {0.f, 0.f, 0.f, 0.f};

    if (fp32) {
        const float* xb = (const float*)Xv + ((size_t)b * GAT_N + row) * GAT_DIN;
        #pragma unroll
        for (int kc = 0; kc < 8; ++kc) {
            float4 x0 = *(const float4*)(xb + kc * 32 + 8 * g);
            float4 x1 = *(const float4*)(xb + kc * 32 + 8 * g + 4);
            bf16x8 af;
            af[0] = (__bf16)x0.x; af[1] = (__bf16)x0.y; af[2] = (__bf16)x0.z; af[3] = (__bf16)x0.w;
            af[4] = (__bf16)x1.x; af[5] = (__bf16)x1.y; af[6] = (__bf16)x1.z; af[7] = (__bf16)x1.w;
            bf16x8 b0 = *(const bf16x8*)&WlF[((kc * 4 + g) * 32 + c) * 8];
            bf16x8 b1 = *(const bf16x8*)&WlF[((kc * 4 + g) * 32 + c + 16) * 8];
            acc0 = __builtin_amdgcn_mfma_f32_16x16x32_bf16(af, b0, acc0, 0, 0, 0);
            acc1 = __builtin_amdgcn_mfma_f32_16x16x32_bf16(af, b1, acc1, 0, 0, 0);
        }
    } else {
        const gu16* xb = (const gu16*)Xv + ((size_t)b * GAT_N + row) * GAT_DIN;
        #pragma unroll
        for (int kc = 0; kc < 8; ++kc) {
            bf16x8 af = *(const bf16x8*)(xb + kc * 32 + 8 * g);
            bf16x8 b0 = *(const bf16x8*)&WlF[((kc * 4 + g) * 32 + c) * 8];
            bf16x8 b1 = *(const bf16x8*)&WlF[((kc * 4 + g) * 32 + c + 16) * 8];
            acc0 = __builtin_amdgcn_mfma_f32_16x16x32_bf16(af, b0, acc0, 0, 0, 0);
            acc1 = __builtin_amdgcn_mfma_f32_16x16x32_bf16(af, b1, acc1, 0, 0, 0);
        }
    }

    // D layout: row = 4*g + q, col = c (HW-verified). Store Whb fragments:
    // rows (nloc+4g .. +3) -> e = (4g&7)+q, kg = ((nloc+4g)>>3)&3, jc = n>>5.
    const int nb = nloc + 4 * g;
    const int jc = nb >> 5, kg = (nb >> 3) & 3, e0 = nb & 7;
    const size_t fb = (((size_t)(b * GAT_H + h) * 32 + jc) * 4 + kg) * 32;
    bf16x4 v0, v1;
    v0[0] = (__bf16)acc0[0]; v0[1] = (__bf16)acc0[1];
    v0[2] = (__bf16)acc0[2]; v0[3] = (__bf16)acc0[3];
    v1[0] = (__bf16)acc1[0]; v1[1] = (__bf16)acc1[1];
    v1[2] = (__bf16)acc1[2]; v1[3] = (__bf16)acc1[3];
    *(bf16x4*)(whb + (fb + c) * 8 + e0)      = v0;
    *(bf16x4*)(whb + (fb + c + 16) * 8 + e0) = v1;

    // e1/e2: dot with a1/a2, reduce over col lanes (bits 0..3).
    float a1c, a1c16, a2c, a2c16;
    if (fp32) {
        const float* ap = (const float*)Av + h * 2 * GAT_HD;
        a1c = ap[c]; a1c16 = ap[c + 16]; a2c = ap[32 + c]; a2c16 = ap[48 + c];
    } else {
        const gu16* ap = (const gu16*)Av + h * 2 * GAT_HD;
        a1c = gb2f(ap[c]); a1c16 = gb2f(ap[c + 16]);
        a2c = gb2f(ap[32 + c]); a2c16 = gb2f(ap[48 + c]);
    }
    float p1[4], p2[4];
    #pragma unroll
    for (int q = 0; q < 4; ++q) {
        p1[q] = acc0[q] * a1c + acc1[q] * a1c16;
        p2[q] = acc0[q] * a2c + acc1[q] * a2c16;
        #pragma unroll
        for (int mm = 1; mm <= 8; mm <<= 1) {
            p1[q] += __shfl_xor(p1[q], mm);
            p2[q] += __shfl_xor(p2[q], mm);
        }
    }
    if (c == 0) {
        const size_t eb = (size_t)(b * GAT_H + h) * GAT_N + nb;
        #pragma unroll
        for (int q = 0; q < 4; ++q) { e1[eb + q] = p1[q]; e2[eb + q] = p2[q]; }
    }
}

// ---------------------------------------------------------------------------
// Kernel 2 (MFMA flash-style): per wave = one head, 16 query rows, full j
// sweep. P fragment built in-register (leaky+exp+mask, bf16), B fragments
// loaded straight from WhbF. Block = 512 thr = 8 heads x same 16 rows
// (adjacency shared across heads via L1). grid = 64 row-tiles x 8 batches,
// b = blockIdx&7 so each XCD keeps one batch's Whb/adj L2-resident.
// ---------------------------------------------------------------------------
__global__ __launch_bounds__(512) void CustomGATLayer_90348932038855_attn(
    const void* __restrict__ Xv, const int* __restrict__ adj, const void* __restrict__ biasv,
    const __bf16* __restrict__ whb, const float* __restrict__ e1f, const float* __restrict__ e2f,
    float* __restrict__ out)
{
    __shared__ __align__(16) float e2l[GAT_H * GAT_N];   // 32 KB
    __shared__ int sflag;

    const int t = threadIdx.x;
    const int h = t >> 6, l = t & 63, g = l >> 4, c = l & 15;
    const int id = blockIdx.x;
    const int b = id & 7, tile = id >> 3;
    const int i0 = tile * 16;

    if (t == 0) sflag = gat_is_fp32((const gu16*)Xv);

    // Stage this head's e2 row (4 KB) into LDS (wave-private slice).
    {
        const float* s = e2f + (size_t)(b * GAT_H + h) * GAT_N;
        float* d = e2l + h * GAT_N;
        #pragma unroll
        for (int q = 0; q < 4; ++q) {
            int off = (q * 64 + l) * 4;
            *(float4*)(d + off) = *(const float4*)(s + off);
        }
    }
    __syncthreads();
    const int fp32 = sflag;

    const float e1r = e1f[(size_t)(b * GAT_H + h) * GAT_N + i0 + c];
    const int* adjr = adj + ((size_t)(b * GAT_N + i0 + c)) * GAT_N + 8 * g;
    const __bf16* whr = whb + (size_t)(b * GAT_H + h) * (GAT_N * GAT_HD) + g * 256 + c * 8;
    const float* e2h = e2l + h * GAT_N + 8 * g;

    // 1-deep prefetch of adjacency + Whb fragments.
    int4 pa0 = *(const int4*)(adjr);
    int4 pa1 = *(const int4*)(adjr + 4);
    bf16x8 pw0 = *(const bf16x8*)(whr);
    bf16x8 pw1 = *(const bf16x8*)(whr + 128);

    f32x4v acc0 = {0.f, 0.f, 0.f, 0.f};
    f32x4v acc1 = {0.f, 0.f, 0.f, 0.f};
    float dsum = 0.f;

#define GAT_WCOMP(EV, AV, IDX) {                    \
        float s_ = e1r + (EV);                      \
        s_ = fmaxf(s_, 0.2f * s_);                  \
        s_ = fminf(s_, 60.0f);                      \
        float w_ = __expf(s_);                      \
        w_ = (AV) ? w_ : 0.0f;                      \
        dsum += w_;                                 \
        pf[IDX] = (__bf16)w_; }

    #pragma unroll 4
    for (int jc = 0; jc < 32; ++jc) {
        int4 a0 = pa0, a1 = pa1;
        bf16x8 w0 = pw0, w1 = pw1;
        if (jc < 31) {
            const int* an = adjr + (jc + 1) * 32;
            pa0 = *(const int4*)(an);
            pa1 = *(const int4*)(an + 4);
            const __bf16* wn = whr + (jc + 1) * 1024;
            pw0 = *(const bf16x8*)(wn);
            pw1 = *(const bf16x8*)(wn + 128);
        }
        float4 ea = *(const float4*)(e2h + jc * 32);
        float4 eb = *(const float4*)(e2h + jc * 32 + 4);
        bf16x8 pf;
        GAT_WCOMP(ea.x, a0.x, 0) GAT_WCOMP(ea.y, a0.y, 1)
        GAT_WCOMP(ea.z, a0.z, 2) GAT_WCOMP(ea.w, a0.w, 3)
        GAT_WCOMP(eb.x, a1.x, 4) GAT_WCOMP(eb.y, a1.y, 5)
        GAT_WCOMP(eb.z, a1.z, 6) GAT_WCOMP(eb.w, a1.w, 7)
        acc0 = __builtin_amdgcn_mfma_f32_16x16x32_bf16(pf, w0, acc0, 0, 0, 0);
        acc1 = __builtin_amdgcn_mfma_f32_16x16x32_bf16(pf, w1, acc1, 0, 0, 0);
    }
#undef GAT_WCOMP

    // dsum(row=c): combine the 4 k-groups.
    dsum += __shfl_xor(dsum, 16);
    dsum += __shfl_xor(dsum, 32);

    float bv0, bv1;
    if (fp32) {
        const float* bp = (const float*)biasv + h * GAT_HD;
        bv0 = bp[c]; bv1 = bp[c + 16];
    } else {
        const gu16* bp = (const gu16*)biasv + h * GAT_HD;
        bv0 = gb2f(bp[c]); bv1 = gb2f(bp[c + 16]);
    }

    float* ob = out + (size_t)(b * GAT_N + i0) * (GAT_H * GAT_HD) + h * GAT_HD + c;
    #pragma unroll
    for (int q = 0; q < 4; ++q) {
        float d = __shfl(dsum, 4 * g + q);      // lanes 0..15 hold dsum(row=lane)
        float r = (d > 0.f) ? (1.0f / d) : 0.0f;
        float o0 = acc0[q] * r + bv0;
        float o1 = acc1[q] * r + bv1;
        o0 = fmaxf(o0, 0.f); o1 = fmaxf(o1, 0.f);
        ob[(size_t)(4 * g + q) * (GAT_H * GAT_HD)]      = o0;
        ob[(size_t)(4 * g + q) * (GAT_H * GAT_HD) + 16] = o1;
    }
}

extern "C" void kernel_launch(void* const* d_in, const int* in_sizes, int n_in,
                              void* d_out, int out_size, void* d_ws, size_t ws_size,
                              hipStream_t stream) {
    const void* X    = d_in[0];              // node_features [8][1024][256]
    const int*  adj  = (const int*)d_in[1];  // adjacency int32 [8][1024][1024]
    const void* Wm   = d_in[2];              // W [8][256][32]
    const void* Av   = d_in[3];              // a [8][64]
    const void* bias = d_in[4];              // bias [256]
    float* outp = (float*)d_out;             // fp32 output (reference dtype)

    __bf16* whb = (__bf16*)d_ws;                                   // 2,097,152 bf16 (4 MB)
    float* e1 = (float*)(whb + (size_t)GAT_B * GAT_H * GAT_N * GAT_HD);
    float* e2 = e1 + (size_t)GAT_B * GAT_H * GAT_N;

    CustomGATLayer_90348932038855_kernel
        <<<dim3(128 * GAT_H), 256, 0, stream>>>(X, Wm, Av, whb, e1, e2);
    CustomGATLayer_90348932038855_attn
        <<<dim3((GAT_N / 16) * GAT_B), 512, 0, stream>>>(
            X, adj, bias, whb, e1, e2, outp);
}

// Round 3
// 134.343 us; speedup vs baseline: 1.5962x; 1.0133x over previous
//
#include <hip/hip_runtime.h>

#define GAT_B   8
#define GAT_N   1024
#define GAT_DIN 256
#define GAT_H   8
#define GAT_HD  32
#define GAT_LOG2E 1.4426950408889634f

typedef unsigned short gu16;
typedef unsigned int   gu32;
typedef __bf16 bf16x8 __attribute__((ext_vector_type(8)));
typedef __bf16 bf16x4 __attribute__((ext_vector_type(4)));
typedef float  f32x4v __attribute__((ext_vector_type(4)));

#if __has_builtin(__builtin_amdgcn_exp2f)
#define GAT_EXP2(x) __builtin_amdgcn_exp2f(x)
#else
#define GAT_EXP2(x) exp2f(x)
#endif

__device__ __forceinline__ float gb2f(gu16 u) { return __uint_as_float(((gu32)u) << 16); }

// Parallel input-dtype self-detection (wave 0, 128 words). bf16 N(0,1):
// exponent <= ~131 in every u16; fp32 mantissa halves hit >=140 w.h.p.
__device__ __forceinline__ void gat_detect(const gu16* p, int t, int* sflag) {
    if (t < 64) {
        int e0 = (p[2 * t]     >> 7) & 0xFF;
        int e1 = (p[2 * t + 1] >> 7) & 0xFF;
        unsigned long long m = __ballot((e0 >= 140) || (e1 >= 140));
        if (t == 0) *sflag = (m != 0ULL);
    }
}

// ---------------------------------------------------------------------------
// Kernel 1 (MFMA): Wh = X @ W[h]; whb written as bf16 B-fragment layout
// WhbF[b][h][jc(32)][kg(4)][col(32)][e(8)] = Wh[jc*32+kg*8+e][col].
// e1 = (Wh.a1)*log2e, e2 = (Wh.a2)*log2e (fp32) -- pre-scaled for exp2.
// Block = 512 thr = 8 waves, one head, 16 row-tiles (W[h] staged ONCE).
// Each wave: 2 tiles, B-fragments reused. grid = 8 h x 32 mg = 256 blocks.
// W LDS layout [kc(8)][k(32)][g(4)][e(8)]: fragment reads are contiguous
// b128 (conflict-free), element (i,k) at ((i>>5)*32+k)*4+((i>>3)&3))*8+(i&7).
// ---------------------------------------------------------------------------
__global__ __launch_bounds__(512) void CustomGATLayer_90348932038855_kernel(
    const void* __restrict__ Xv, const void* __restrict__ Wv, const void* __restrict__ Av,
    __bf16* __restrict__ whb, float* __restrict__ e1, float* __restrict__ e2)
{
    __shared__ __align__(16) __bf16 WlF[GAT_DIN * GAT_HD];   // 16 KB
    __shared__ int sflag;

    const int t  = threadIdx.x;
    const int id = blockIdx.x;
    const int h  = id >> 5;                 // 0..7
    const int mg = id & 31;                 // 0..31

    gat_detect((const gu16*)Xv, t, &sflag);
    __syncthreads();
    const int fp32 = sflag;

    // Stage W[h] (256x32) into fragment layout; 16 elems per thread.
    if (fp32) {
        const float* ws = (const float*)Wv + (size_t)h * GAT_DIN * GAT_HD;
        #pragma unroll
        for (int q = 0; q < 4; ++q) {
            int idx = q * 2048 + t * 4;
            int i = idx >> 5, k = idx & 31;
            float4 v = *(const float4*)(ws + idx);
            int d = (((i >> 5) * 32 + k) * 4 + ((i >> 3) & 3)) * 8 + (i & 7);
            WlF[d] = (__bf16)v.x; WlF[d + 32] = (__bf16)v.y;
            WlF[d + 64] = (__bf16)v.z; WlF[d + 96] = (__bf16)v.w;
        }
    } else {
        const gu16* ws = (const gu16*)Wv + (size_t)h * GAT_DIN * GAT_HD;
        gu16* wl = (gu16*)WlF;
        #pragma unroll
        for (int q = 0; q < 4; ++q) {
            int idx = q * 2048 + t * 4;
            int i = idx >> 5, k = idx & 31;
            ushort4 v = *(const ushort4*)(ws + idx);
            int d = (((i >> 5) * 32 + k) * 4 + ((i >> 3) & 3)) * 8 + (i & 7);
            wl[d] = v.x; wl[d + 32] = v.y; wl[d + 64] = v.z; wl[d + 96] = v.w;
        }
    }
    __syncthreads();

    const int wid = t >> 6, l = t & 63, g = l >> 4, c = l & 15;

    // B fragments for this wave (reused by both tiles): contiguous b128 reads.
    bf16x8 bf0[8], bf1[8];
    #pragma unroll
    for (int kc = 0; kc < 8; ++kc) {
        bf0[kc] = *(const bf16x8*)&WlF[((kc * 32 + c) * 4 + g) * 8];
        bf1[kc] = *(const bf16x8*)&WlF[((kc * 32 + c + 16) * 4 + g) * 8];
    }

    float a1c, a1c16, a2c, a2c16;
    if (fp32) {
        const float* ap = (const float*)Av + h * 2 * GAT_HD;
        a1c = ap[c] * GAT_LOG2E;      a1c16 = ap[c + 16] * GAT_LOG2E;
        a2c = ap[32 + c] * GAT_LOG2E; a2c16 = ap[48 + c] * GAT_LOG2E;
    } else {
        const gu16* ap = (const gu16*)Av + h * 2 * GAT_HD;
        a1c = gb2f(ap[c]) * GAT_LOG2E;      a1c16 = gb2f(ap[c + 16]) * GAT_LOG2E;
        a2c = gb2f(ap[32 + c]) * GAT_LOG2E; a2c16 = gb2f(ap[48 + c]) * GAT_LOG2E;
    }

    #pragma unroll
    for (int tt = 0; tt < 2; ++tt) {
        const int mt   = mg * 16 + wid * 2 + tt;   // 0..511
        const int M0   = mt * 16;
        const int b    = M0 >> 10;
        const int nloc = M0 & 1023;
        const int row  = nloc + c;

        f32x4v acc0 = {0.f, 0.f, 0.f, 0.f};
        f32x4v acc1 = {0.f, 0.f, 0.f, 0.f};

        if (fp32) {
            const float* xb = (const float*)Xv + ((size_t)b * GAT_N + row) * GAT_DIN;
            #pragma unroll
            for (int kc = 0; kc < 8; ++kc) {
                float4 x0 = *(const float4*)(xb + kc * 32 + 8 * g);
                float4 x1 = *(const float4*)(xb + kc * 32 + 8 * g + 4);
                bf16x8 af;
                af[0] = (__bf16)x0.x; af[1] = (__bf16)x0.y; af[2] = (__bf16)x0.z; af[3] = (__bf16)x0.w;
                af[4] = (__bf16)x1.x; af[5] = (__bf16)x1.y; af[6] = (__bf16)x1.z; af[7] = (__bf16)x1.w;
                acc0 = __builtin_amdgcn_mfma_f32_16x16x32_bf16(af, bf0[kc], acc0, 0, 0, 0);
                acc1 = __builtin_amdgcn_mfma_f32_16x16x32_bf16(af, bf1[kc], acc1, 0, 0, 0);
            }
        } else {
            const gu16* xb = (const gu16*)Xv + ((size_t)b * GAT_N + row) * GAT_DIN;
            #pragma unroll
            for (int kc = 0; kc < 8; ++kc) {
                bf16x8 af = *(const bf16x8*)(xb + kc * 32 + 8 * g);
                acc0 = __builtin_amdgcn_mfma_f32_16x16x32_bf16(af, bf0[kc], acc0, 0, 0, 0);
                acc1 = __builtin_amdgcn_mfma_f32_16x16x32_bf16(af, bf1[kc], acc1, 0, 0, 0);
            }
        }

        // D layout: row = 4*g + q, col = c. Store Whb fragments.
        const int nb = nloc + 4 * g;
        const int jcc = nb >> 5, kg = (nb >> 3) & 3, e0 = nb & 7;
        const size_t fb = (((size_t)(b * GAT_H + h) * 32 + jcc) * 4 + kg) * 32;
        bf16x4 v0, v1;
        v0[0] = (__bf16)acc0[0]; v0[1] = (__bf16)acc0[1];
        v0[2] = (__bf16)acc0[2]; v0[3] = (__bf16)acc0[3];
        v1[0] = (__bf16)acc1[0]; v1[1] = (__bf16)acc1[1];
        v1[2] = (__bf16)acc1[2]; v1[3] = (__bf16)acc1[3];
        *(bf16x4*)(whb + (fb + c) * 8 + e0)      = v0;
        *(bf16x4*)(whb + (fb + c + 16) * 8 + e0) = v1;

        // e1/e2 (pre-scaled by log2e): reduce over col lanes (bits 0..3).
        float p1[4], p2[4];
        #pragma unroll
        for (int q = 0; q < 4; ++q) {
            p1[q] = acc0[q] * a1c + acc1[q] * a1c16;
            p2[q] = acc0[q] * a2c + acc1[q] * a2c16;
            #pragma unroll
            for (int mm = 1; mm <= 8; mm <<= 1) {
                p1[q] += __shfl_xor(p1[q], mm);
                p2[q] += __shfl_xor(p2[q], mm);
            }
        }
        if (c == 0) {
            const size_t eb = (size_t)(b * GAT_H + h) * GAT_N + nb;
            #pragma unroll
            for (int q = 0; q < 4; ++q) { e1[eb + q] = p1[q]; e2[eb + q] = p2[q]; }
        }
    }
}

// ---------------------------------------------------------------------------
// Kernel 2 (MFMA flash-style): per wave = one head, 16 query rows, full j
// sweep. Row-sums via a 3rd MFMA against an all-ones B fragment (no VALU
// dsum, no epilogue shuffles). 3-deep adjacency / 2-deep Whb prefetch.
// Block = 512 thr = 8 heads x same 16 rows. grid = 64 tiles x 8 b,
// b = id&7 -> batch pinned to XCD (Whb/adj L2-resident).
// ---------------------------------------------------------------------------
__global__ __launch_bounds__(512) void CustomGATLayer_90348932038855_attn(
    const void* __restrict__ Xv, const int* __restrict__ adj, const void* __restrict__ biasv,
    const __bf16* __restrict__ whb, const float* __restrict__ e1f, const float* __restrict__ e2f,
    float* __restrict__ out)
{
    __shared__ __align__(16) float e2l[GAT_H * GAT_N];   // 32 KB
    __shared__ int sflag;

    const int t = threadIdx.x;
    const int h = t >> 6, l = t & 63, g = l >> 4, c = l & 15;
    const int id = blockIdx.x;
    const int b = id & 7, tile = id >> 3;
    const int i0 = tile * 16;

    gat_detect((const gu16*)Xv, t, &sflag);

    // Stage this head's e2 row (4 KB, pre-scaled by log2e) into LDS.
    {
        const float* s = e2f + (size_t)(b * GAT_H + h) * GAT_N;
        float* d = e2l + h * GAT_N;
        #pragma unroll
        for (int q = 0; q < 4; ++q) {
            int off = (q * 64 + l) * 4;
            *(float4*)(d + off) = *(const float4*)(s + off);
        }
    }
    __syncthreads();
    const int fp32 = sflag;

    const float e1r = e1f[(size_t)(b * GAT_H + h) * GAT_N + i0 + c];
    const int* adjr = adj + ((size_t)(b * GAT_N + i0 + c)) * GAT_N + 8 * g;
    const __bf16* whr = whb + (size_t)(b * GAT_H + h) * (GAT_N * GAT_HD) + g * 256 + c * 8;
    const float* e2h = e2l + h * GAT_N + 8 * g;

    // Prefetch: adjacency 3-deep (HBM latency), Whb 2-deep (L2-resident).
    int4 aA0 = *(const int4*)(adjr),      aA1 = *(const int4*)(adjr + 4);
    int4 aB0 = *(const int4*)(adjr + 32), aB1 = *(const int4*)(adjr + 36);
    int4 aC0 = *(const int4*)(adjr + 64), aC1 = *(const int4*)(adjr + 68);
    bf16x8 wA0 = *(const bf16x8*)(whr),        wA1 = *(const bf16x8*)(whr + 128);
    bf16x8 wB0 = *(const bf16x8*)(whr + 1024), wB1 = *(const bf16x8*)(whr + 1152);

    f32x4v acc0 = {0.f, 0.f, 0.f, 0.f};
    f32x4v acc1 = {0.f, 0.f, 0.f, 0.f};
    f32x4v accS = {0.f, 0.f, 0.f, 0.f};
    bf16x8 onesf;
    #pragma unroll
    for (int e = 0; e < 8; ++e) onesf[e] = (__bf16)1.0f;

#define GAT_WCOMP(EV, AV, IDX) {                    \
        float s_ = e1r + (EV);                      \
        s_ = fmaxf(s_, 0.2f * s_);                  \
        s_ = fminf(s_, 86.0f);                      \
        float w_ = GAT_EXP2(s_);                    \
        w_ = (AV) ? w_ : 0.0f;                      \
        pf[IDX] = (__bf16)w_; }

    #pragma unroll 2
    for (int jc = 0; jc < 32; ++jc) {
        const int4 a0 = aA0, a1 = aA1;
        const bf16x8 w0 = wA0, w1 = wA1;
        aA0 = aB0; aA1 = aB1; aB0 = aC0; aB1 = aC1;
        wA0 = wB0; wA1 = wB1;
        if (jc < 29) {
            const int* an = adjr + (jc + 3) * 32;
            aC0 = *(const int4*)an; aC1 = *(const int4*)(an + 4);
        }
        if (jc < 30) {
            const __bf16* wn = whr + (jc + 2) * 1024;
            wB0 = *(const bf16x8*)wn; wB1 = *(const bf16x8*)(wn + 128);
        }
        float4 ea = *(const float4*)(e2h + jc * 32);
        float4 eb = *(const float4*)(e2h + jc * 32 + 4);
        bf16x8 pf;
        GAT_WCOMP(ea.x, a0.x, 0) GAT_WCOMP(ea.y, a0.y, 1)
        GAT_WCOMP(ea.z, a0.z, 2) GAT_WCOMP(ea.w, a0.w, 3)
        GAT_WCOMP(eb.x, a1.x, 4) GAT_WCOMP(eb.y, a1.y, 5)
        GAT_WCOMP(eb.z, a1.z, 6) GAT_WCOMP(eb.w, a1.w, 7)
        acc0 = __builtin_amdgcn_mfma_f32_16x16x32_bf16(pf, w0, acc0, 0, 0, 0);
        acc1 = __builtin_amdgcn_mfma_f32_16x16x32_bf16(pf, w1, acc1, 0, 0, 0);
        accS = __builtin_amdgcn_mfma_f32_16x16x32_bf16(pf, onesf, accS, 0, 0, 0);
    }
#undef GAT_WCOMP

    float bv0, bv1;
    if (fp32) {
        const float* bp = (const float*)biasv + h * GAT_HD;
        bv0 = bp[c]; bv1 = bp[c + 16];
    } else {
        const gu16* bp = (const gu16*)biasv + h * GAT_HD;
        bv0 = gb2f(bp[c]); bv1 = gb2f(bp[c + 16]);
    }

    // accS[q] holds the row-sum for row 4g+q in EVERY column -> no shuffles.
    float* ob = out + (size_t)(b * GAT_N + i0) * (GAT_H * GAT_HD) + h * GAT_HD + c;
    #pragma unroll
    for (int q = 0; q < 4; ++q) {
        float d = accS[q];
        float r = (d > 0.f) ? (1.0f / d) : 0.0f;
        float o0 = fmaxf(acc0[q] * r + bv0, 0.f);
        float o1 = fmaxf(acc1[q] * r + bv1, 0.f);
        ob[(size_t)(4 * g + q) * (GAT_H * GAT_HD)]      = o0;
        ob[(size_t)(4 * g + q) * (GAT_H * GAT_HD) + 16] = o1;
    }
}

extern "C" void kernel_launch(void* const* d_in, const int* in_sizes, int n_in,
                              void* d_out, int out_size, void* d_ws, size_t ws_size,
                              hipStream_t stream) {
    const void* X    = d_in[0];              // node_features [8][1024][256]
    const int*  adj  = (const int*)d_in[1];  // adjacency int32 [8][1024][1024]
    const void* Wm   = d_in[2];              // W [8][256][32]
    const void* Av   = d_in[3];              // a [8][64]
    const void* bias = d_in[4];              // bias [256]
    float* outp = (float*)d_out;             // fp32 output (reference dtype)

    __bf16* whb = (__bf16*)d_ws;                                   // 4 MB
    float* e1 = (float*)(whb + (size_t)GAT_B * GAT_H * GAT_N * GAT_HD);
    float* e2 = e1 + (size_t)GAT_B * GAT_H * GAT_N;

    CustomGATLayer_90348932038855_kernel
        <<<dim3(8 * 32), 512, 0, stream>>>(X, Wm, Av, whb, e1, e2);
    CustomGATLayer_90348932038855_attn
        <<<dim3((GAT_N / 16) * GAT_B), 512, 0, stream>>>(
            X, adj, bias, whb, e1, e2, outp);
}